// Round 11
// baseline (170.011 us; speedup 1.0000x reference)
//
#include <hip/hip_runtime.h>

#define NB 4
#define CIN 64
#define COUT 64
#define H 128
#define W 128
#define H2 256
#define W2 256
#define HSX 23            // halo row stride (uint2 units)
#define ZS 40             // zbuf row stride (ushorts) = 80B, 16B-aligned rows

// ws layout (float units)
#define WS_W    0         // bf16 weights ushort[32][64][32] = 32768 floats
#define WS_P1   32768     // per-tile partial sums  [4*64][256]
#define WS_P2   98304     // per-tile partial sumsq [4*64][256]
#define WS_MU   163840
#define WS_RSTD 164096

// ---------------------------------------------------------------------------
// Compile-time DISCO basis (replicates the numpy double-precision computation)
// ---------------------------------------------------------------------------
constexpr double csqrt(double x) {
    double g = x > 1.0 ? x : 1.0;
    for (int i = 0; i < 64; ++i) g = 0.5 * (g + x / g);
    return g;
}
constexpr double catan_pos(double x) {
    double f = 1.0;
    for (int i = 0; i < 6; ++i) { x = x / (1.0 + csqrt(1.0 + x * x)); f *= 2.0; }
    double x2 = x * x, s = 0.0, term = x;
    for (int n = 0; n < 10; ++n) { s += term / (2 * n + 1) * ((n & 1) ? -1.0 : 1.0); term *= x2; }
    return f * s;
}
constexpr double catan2c(double y, double x) {
    const double PI = 3.141592653589793;
    if (x == 0.0 && y == 0.0) return 0.0;
    double ax = x < 0 ? -x : x, ay = y < 0 ? -y : y;
    double a = (ax >= ay) ? catan_pos(ay / ax) : (PI / 2.0 - catan_pos(ax / ay));
    if (x < 0) a = PI - a;
    return (y < 0) ? -a : a;
}

struct PsiTab { double v[81][9]; };
constexpr PsiTab compute_psi() {
    PsiTab P{};
    const double hy = 1.0 / 256.0;
    const double rcut = 0.015;
    const double dr = 0.0075;
    const double PI = 3.141592653589793;
    const double TWO_PI = 6.283185307179586;
    const double dphi = PI / 2.0;
    for (int ky = 0; ky < 9; ++ky)
        for (int kx = 0; kx < 9; ++kx) {
            double dy = (double)(ky - 4) * hy;
            double dx = (double)(kx - 4) * hy;
            double r = csqrt(dy * dy + dx * dx);
            double phi = catan2c(dy, dx);
            if (phi < 0.0) phi += TWO_PI;
            for (int k = 0; k < 9; ++k) {
                int ir = (k == 0) ? 0 : ((k - 1) / 4 + 1);
                double ctr = ir * dr;
                double ad = r > ctr ? r - ctr : ctr - r;
                double rv = (ad <= dr && r <= rcut) ? 1.0 - ad / dr : 0.0;
                double val;
                if (k == 0) val = rv;
                else {
                    int ip = (k - 1) % 4;
                    double da = phi - ip * dphi; if (da < 0) da = -da;
                    double d2 = TWO_PI - da; if (d2 < da) da = d2;
                    double pv = (da <= dphi) ? 1.0 - da / dphi : 0.0;
                    val = rv * pv;
                }
                P.v[ky * 9 + kx][k] = val * (hy * hy);
            }
        }
    return P;
}

struct TapTab {
    int nt;
    int off[48];          // dy*HSX + dx (uint2 offset from thread base)
    float val[48][9];
    bool nz[48][9];
};
constexpr TapTab make_taps() {
    TapTab T{};
    PsiTab P = compute_psi();
    for (int ky = 0; ky < 9; ++ky)
        for (int kx = 0; kx < 9; ++kx) {
            int t = ky * 9 + kx;
            bool any = false;
            for (int k = 0; k < 9; ++k) if (P.v[t][k] != 0.0) any = true;
            if (!any) continue;
            int dy = ky - 4, dx = kx - 4;    // support guarantees |dy|,|dx| <= 3
            T.off[T.nt] = dy * HSX + dx;
            for (int k = 0; k < 9; ++k) {
                T.val[T.nt][k] = (float)P.v[t][k];
                T.nz[T.nt][k] = (P.v[t][k] != 0.0);
            }
            T.nt++;
        }
    return T;
}
constexpr TapTab TT = make_taps();
constexpr int NT = TT.nt;
static_assert(NT > 0 && NT <= 48, "tap table overflow");

using f32x2  = __attribute__((ext_vector_type(2))) float;
using f32x4  = __attribute__((ext_vector_type(4))) float;
using bf16x8 = __attribute__((ext_vector_type(8))) short;

__device__ __forceinline__ unsigned short f2bf_rne(float f) {
    unsigned u = __float_as_uint(f);
    unsigned r = (u + 0x7fff + ((u >> 16) & 1)) >> 16;
    return (unsigned short)r;
}
// RTZ pack of two floats to one u32 of 2 bf16 (bias cancels in InstanceNorm)
__device__ __forceinline__ unsigned pkrtz(float a, float b) {
    return (__float_as_uint(a) >> 16) | (__float_as_uint(b) & 0xffff0000u);
}

// ---------------------------------------------------------------------------
// Setup: pre-transpose weights to bf16 wsW[j][o][32]  (kk = ch*16 + k, pads 0)
// pair j covers input channels 2j, 2j+1
// ---------------------------------------------------------------------------
__global__ void setup_w(const float* __restrict__ wgt, float* __restrict__ ws) {
    unsigned short* wsW = (unsigned short*)(ws + WS_W);
    const int g = blockIdx.x;          // channel pair 0..31
    const int t = threadIdx.x;         // 256
    const int o = t >> 2;
    const int k0 = (t & 3) * 8;
#pragma unroll
    for (int j = 0; j < 8; ++j) {
        int kk = k0 + j;
        int ch = kk >> 4, k = kk & 15;
        float v = (k < 9) ? wgt[((size_t)o * CIN + 2 * g + ch) * 9 + k] : 0.f;
        wsW[g * 2048 + o * 32 + kk] = f2bf_rne(v);
    }
}

// ---------------------------------------------------------------------------
// Fused upsample + DISCO conv. Block = 16x16 px tile (256 px), 4 waves.
// QUAD-channel groups (16 of them): halo element = uint2{bf16 ch0,ch1 | ch2,ch3}
// so ONE b64 tap read feeds 4 channels. zphase computes z01 (->zbuf[0]) and
// z23 (18 regs, ->zbuf[1] next phase). 2 barriers/group; halo/coarse single-
// buffered (alternating read/write phases); zbuf parity = MFMA K-step parity.
// ---------------------------------------------------------------------------
__global__ __launch_bounds__(256, 2) void conv_kernel(const float* __restrict__ img,
                                                      float* __restrict__ out,
                                                      float* __restrict__ ws) {
    __shared__ __align__(16) unsigned short zbuf[2][256][ZS]; // [kstep][px][kk]
    __shared__ uint2 halo[22 * HSX];           // {ch01, ch23} bf16-paired
    __shared__ f32x2 coarse01[14 * 15];
    __shared__ f32x2 coarse23[14 * 15];
    __shared__ float red1[4][64], red2[4][64];

    const int tid  = threadIdx.x;
    const int bid  = blockIdx.x;
    const int n    = bid >> 8;
    const int tile = bid & 255;
    const int ty0  = (tile >> 4) << 4;
    const int tx0  = (tile & 15) << 4;

    const int r = tid >> 4, c = tid & 15;
    const int hbase = (r + 3) * HSX + (c + 3);
    const int wv  = tid >> 6;
    const int l   = tid & 63;
    const int a16 = l & 15;
    const int kseg = (l >> 4) * 8;

    const unsigned short* wsW = (const unsigned short*)(ws + WS_W);

    // zero both zbuf k-step buffers once (kk pads stay zero forever)
    {
        uint4* zr = (uint4*)&zbuf[0][0][0];
#pragma unroll
        for (int j = 0; j < 10; ++j) zr[tid + j * 256] = make_uint4(0, 0, 0, 0);
    }

    const float cs = 0.49803922f;   // 127/255

    // ---- block-constant coarse patch base ----
    int cy0 = (int)floorf((float)(ty0 - 3) * cs); cy0 = min(max(cy0, 0), 114);
    int cx0 = (int)floorf((float)(tx0 - 3) * cs); cx0 = min(max(cx0, 0), 114);

    // ---- coarse loader invariants (1 elem/thread, 196 used, 4 channels) ----
    const bool cok = tid < 196;
    const int ci = tid / 14, cj = tid - ci * 14;
    const int cgoff = (cy0 + ci) * W + (cx0 + cj);
    const int cwidx = ci * 15 + cj;
    float cv0 = 0.f, cv1 = 0.f, cv2 = 0.f, cv3 = 0.f;

    auto cload = [&](int g4) {                 // channels 4*g4 .. 4*g4+3
        if (cok) {
            const float* b = img + ((size_t)n * CIN + 4 * g4) * (H * W) + cgoff;
            cv0 = b[0];
            cv1 = b[H * W];
            cv2 = b[2 * H * W];
            cv3 = b[3 * H * W];
        }
    };
    auto cwrite = [&]() {
        if (cok) {
            coarse01[cwidx] = (f32x2){cv0, cv1};
            coarse23[cwidx] = (f32x2){cv2, cv3};
        }
    };

    // ---- fine-halo metadata: 484 elems, 2 slots, packed u32 + fy + fx ----
    unsigned fM[2];
    float fFY[2], fFX[2];
#pragma unroll
    for (int j = 0; j < 2; ++j) {
        int e = tid + j * 256;
        if (e < 484) {
            int hy = e / 22, hx = e - hy * 22;
            int uy = ty0 - 3 + hy, ux = tx0 - 3 + hx;
            unsigned zf = (((unsigned)uy >= 256u) || ((unsigned)ux >= 256u)) ? 1u : 0u;
            float syf = (float)uy * cs;
            float sxf = (float)ux * cs;
            int y0 = (int)floorf(syf);
            int x0 = (int)floorf(sxf);
            fFY[j] = syf - (float)y0;
            fFX[j] = sxf - (float)x0;
            int y0c = min(max(y0, 0), 127), x0c = min(max(x0, 0), 127);
            int dyo = min(y0c + 1, 127) - y0c;            // 0/1
            int dxo = min(x0c + 1, 127) - x0c;            // 0/1
            unsigned A = (unsigned)((y0c - cy0) * 15 + (x0c - cx0));
            fM[j] = A | ((unsigned)dxo << 9) | ((unsigned)dyo << 10) | (zf << 11)
                      | ((unsigned)(hy * HSX + hx) << 12);
        }
    }

    auto fine_build = [&]() {
#pragma unroll
        for (int j = 0; j < 2; ++j)
            if (tid < 484 - j * 256) {
                unsigned m = fM[j];
                int A = m & 511;
                int dxo = (m >> 9) & 1;
                int dyo = ((m >> 10) & 1) * 15;
                f32x2 fyv = (f32x2){fFY[j], fFY[j]};
                f32x2 fxv = (f32x2){fFX[j], fFX[j]};
                f32x2 a00 = coarse01[A],       a01 = coarse01[A + dxo];
                f32x2 a10 = coarse01[A + dyo], a11 = coarse01[A + dyo + dxo];
                f32x2 t0 = a00 + fyv * (a10 - a00);
                f32x2 t1 = a01 + fyv * (a11 - a01);
                f32x2 v01 = t0 + fxv * (t1 - t0);
                f32x2 b00 = coarse23[A],       b01 = coarse23[A + dxo];
                f32x2 b10 = coarse23[A + dyo], b11 = coarse23[A + dyo + dxo];
                f32x2 u0 = b00 + fyv * (b10 - b00);
                f32x2 u1 = b01 + fyv * (b11 - b01);
                f32x2 v23 = u0 + fxv * (u1 - u0);
                if (m & (1u << 11)) { v01 = (f32x2){0.f, 0.f}; v23 = (f32x2){0.f, 0.f}; }
                halo[m >> 12] = make_uint2(
                    (unsigned)f2bf_rne(v01.x) | ((unsigned)f2bf_rne(v01.y) << 16),
                    (unsigned)f2bf_rne(v23.x) | ((unsigned)f2bf_rne(v23.y) << 16));
            }
    };

    f32x2 z23[9];   // carried from phase A (compute) to phase B (store)

    auto zphase4 = [&]() {
        const uint2* hb = &halo[hbase - 72];   // all imm offsets >= 0
        f32x2 z01[9];
#pragma unroll
        for (int k = 0; k < 9; ++k) { z01[k] = (f32x2){0.f, 0.f}; z23[k] = (f32x2){0.f, 0.f}; }
#pragma unroll
        for (int t = 0; t < NT; ++t) {
            uint2 d = hb[72 + TT.off[t]];
            f32x2 h01, h23;
            h01.x = __uint_as_float(d.x << 16);
            h01.y = __uint_as_float(d.x & 0xffff0000u);
            h23.x = __uint_as_float(d.y << 16);
            h23.y = __uint_as_float(d.y & 0xffff0000u);
#pragma unroll
            for (int k = 0; k < 9; ++k)
                if (TT.nz[t][k]) {
                    z01[k] += h01 * TT.val[t][k];   // v_pk_fma_f32
                    z23[k] += h23 * TT.val[t][k];
                }
        }
        unsigned short* zr = &zbuf[0][tid][0];
        *(uint4*)zr = make_uint4(pkrtz(z01[0].x, z01[1].x), pkrtz(z01[2].x, z01[3].x),
                                 pkrtz(z01[4].x, z01[5].x), pkrtz(z01[6].x, z01[7].x));
        zr[8] = (unsigned short)(__float_as_uint(z01[8].x) >> 16);
        *(uint4*)(zr + 16) = make_uint4(pkrtz(z01[0].y, z01[1].y), pkrtz(z01[2].y, z01[3].y),
                                        pkrtz(z01[4].y, z01[5].y), pkrtz(z01[6].y, z01[7].y));
        zr[24] = (unsigned short)(__float_as_uint(z01[8].y) >> 16);
    };
    auto writez23 = [&]() {
        unsigned short* zr = &zbuf[1][tid][0];
        *(uint4*)zr = make_uint4(pkrtz(z23[0].x, z23[1].x), pkrtz(z23[2].x, z23[3].x),
                                 pkrtz(z23[4].x, z23[5].x), pkrtz(z23[6].x, z23[7].x));
        zr[8] = (unsigned short)(__float_as_uint(z23[8].x) >> 16);
        *(uint4*)(zr + 16) = make_uint4(pkrtz(z23[0].y, z23[1].y), pkrtz(z23[2].y, z23[3].y),
                                        pkrtz(z23[4].y, z23[5].y), pkrtz(z23[6].y, z23[7].y));
        zr[24] = (unsigned short)(__float_as_uint(z23[8].y) >> 16);
    };

    f32x4 acc[4][4];
#pragma unroll
    for (int m = 0; m < 4; ++m)
#pragma unroll
        for (int t = 0; t < 4; ++t) acc[m][t] = (f32x4){0.f, 0.f, 0.f, 0.f};

    auto mfma_step = [&](int j) {              // pair j = channels 2j, 2j+1
        const int zp = j & 1;
        bf16x8 af[4];
        const unsigned short* wp = wsW + j * 2048 + a16 * 32 + kseg;
#pragma unroll
        for (int m = 0; m < 4; ++m)
            af[m] = *(const bf16x8*)(wp + m * 512);
        union { uint4 q4; bf16x8 v; } bfr;
#pragma unroll
        for (int t = 0; t < 4; ++t) {
            bfr.q4 = *(const uint4*)&zbuf[zp][wv * 64 + t * 16 + a16][kseg];
#pragma unroll
            for (int m = 0; m < 4; ++m)
                acc[m][t] = __builtin_amdgcn_mfma_f32_16x16x32_bf16(af[m], bfr.v, acc[m][t], 0, 0, 0);
        }
    };

    // ---- prologue: coarse(0) -> halo(0) ----
    cload(0); cwrite();
    __syncthreads();
    fine_build();
    __syncthreads();

#pragma unroll 1
    for (int g = 0; g < 16; ++g) {
        // phase A: MFMA ch23(g-1); compute z01,z23 of group g; stage coarse(g+1)
        if (g > 0) mfma_step(2 * g - 1);
        if (g < 15) cload(g + 1);
        zphase4();                 // reads halo(g), writes zbuf[0]
        if (g < 15) cwrite();      // regs -> coarse(g+1)
        __syncthreads();
        // phase B: MFMA ch01(g); store z23; build halo(g+1)
        mfma_step(2 * g);
        writez23();                // -> zbuf[1]
        if (g < 15) fine_build();  // coarse(g+1) -> halo(g+1)
        __syncthreads();
    }
    mfma_step(31);                 // ch23 of group 15 (zbuf[1])

    // ---- epilogue: instance-norm partials + store y ----
#pragma unroll
    for (int m = 0; m < 4; ++m) {
#pragma unroll
        for (int r4 = 0; r4 < 4; ++r4) {
            float s = 0.f, q = 0.f;
#pragma unroll
            for (int t = 0; t < 4; ++t) {
                float v = acc[m][t][r4];
                s += v; q = fmaf(v, v, q);
            }
#pragma unroll
            for (int msk = 1; msk < 16; msk <<= 1) {
                s += __shfl_xor(s, msk);
                q += __shfl_xor(q, msk);
            }
            if (a16 == 0) {
                int o = m * 16 + (l >> 4) * 4 + r4;
                red1[wv][o] = s;
                red2[wv][o] = q;
            }
        }
    }

    const size_t nbase = (size_t)n * COUT * (H2 * W2);
#pragma unroll
    for (int m = 0; m < 4; ++m)
#pragma unroll
        for (int t = 0; t < 4; ++t) {
            int Y = ty0 + wv * 4 + t;
            int X = tx0 + a16;
#pragma unroll
            for (int r4 = 0; r4 < 4; ++r4) {
                int o = m * 16 + (l >> 4) * 4 + r4;
                out[nbase + (size_t)o * (H2 * W2) + Y * W2 + X] = acc[m][t][r4];
            }
        }
    __syncthreads();
    if (tid < 64) {
        float S1 = red1[0][tid] + red1[1][tid] + red1[2][tid] + red1[3][tid];
        float S2 = red2[0][tid] + red2[1][tid] + red2[2][tid] + red2[3][tid];
        ws[WS_P1 + (n * COUT + tid) * 256 + tile] = S1;
        ws[WS_P2 + (n * COUT + tid) * 256 + tile] = S2;
    }
}

// ---------------------------------------------------------------------------
// Stats: reduce 256 tile-partials per (n,c)
// ---------------------------------------------------------------------------
__global__ void stats_kernel(float* __restrict__ ws) {
    const int co  = blockIdx.x;
    const int tid = threadIdx.x;   // 256
    float s1 = ws[WS_P1 + co * 256 + tid];
    float s2 = ws[WS_P2 + co * 256 + tid];
#pragma unroll
    for (int m = 1; m < 64; m <<= 1) { s1 += __shfl_xor(s1, m); s2 += __shfl_xor(s2, m); }
    __shared__ float r1[4], r2[4];
    if ((tid & 63) == 0) { r1[tid >> 6] = s1; r2[tid >> 6] = s2; }
    __syncthreads();
    if (tid == 0) {
        float S1 = r1[0] + r1[1] + r1[2] + r1[3];
        float S2 = r2[0] + r2[1] + r2[2] + r2[3];
        const float inv = 1.f / 65536.f;
        float mu  = S1 * inv;
        float var = S2 * inv - mu * mu;
        ws[WS_MU + co]   = mu;
        ws[WS_RSTD + co] = 1.f / sqrtf(var + 1e-5f);
    }
}

// ---------------------------------------------------------------------------
// Normalize + LeakyReLU(0.2), in place on d_out
// ---------------------------------------------------------------------------
__global__ void norm_kernel(float* __restrict__ out, const float* __restrict__ ws) {
    const int total = NB * COUT * H2 * W2 / 4;
    for (int idx = blockIdx.x * blockDim.x + threadIdx.x; idx < total;
         idx += gridDim.x * blockDim.x) {
        int co = idx >> 14;
        float mu = ws[WS_MU + co];
        float rs = ws[WS_RSTD + co];
        float4 v = ((float4*)out)[idx];
        float* p = (float*)&v;
#pragma unroll
        for (int j = 0; j < 4; ++j) {
            float t = (p[j] - mu) * rs;
            p[j] = (t >= 0.f) ? t : 0.2f * t;
        }
        ((float4*)out)[idx] = v;
    }
}

extern "C" void kernel_launch(void* const* d_in, const int* in_sizes, int n_in,
                              void* d_out, int out_size, void* d_ws, size_t ws_size,
                              hipStream_t stream) {
    const float* img = (const float*)d_in[0];
    const float* wgt = (const float*)d_in[1];
    float* out = (float*)d_out;
    float* ws  = (float*)d_ws;

    setup_w<<<32, 256, 0, stream>>>(wgt, ws);
    conv_kernel<<<NB * 256, 256, 0, stream>>>(img, out, ws);
    stats_kernel<<<256, 256, 0, stream>>>(ws);
    norm_kernel<<<2048, 256, 0, stream>>>(out, ws);
}